// Round 8
// baseline (2729.456 us; speedup 1.0000x reference)
//
#include <hip/hip_runtime.h>
#include <cstddef>
#include <cstdint>

namespace {

constexpr int N   = 50000;
constexpr int E   = 800000;
constexpr int IN  = 256;
constexpr int H   = 128;
constexpr int H2v = 64;
constexpr int O   = 32;
constexpr int K   = 5;
constexpr float ALPHA = 0.1f;
constexpr float EPS   = 1e-5f;
constexpr int NPAD = 50048;
constexpr int CAP  = 48;             // fixed CSR capacity per node (deg~Poisson(16))
constexpr int Q1 = 12500, Q2 = 25000, Q3 = 37500;   // src quartiles (N/4)
constexpr int PROP_BLOCKS = 1024;    // 4 blocks/CU -> fully co-resident
constexpr int NPW = 13;              // nodes per wave: 1024*4*13 = 53248 >= NPAD
constexpr int FILL_BLOCKS = (E + 255) / 256;   // 3125
constexpr int MLP_BLOCKS  = NPAD / 64;         // 782
constexpr int NORM_BLOCKS = NPAD / 4;          // 12512

typedef __bf16 bf16x8 __attribute__((ext_vector_type(8)));
typedef float  f32x4  __attribute__((ext_vector_type(4)));

__device__ inline uint32_t pack2_bf16(float x, float y) {
  uint32_t ux = __float_as_uint(x);
  uint32_t uy = __float_as_uint(y);
  ux = (ux + 0x7FFFu + ((ux >> 16) & 1u)) >> 16;
  uy = (uy + 0x7FFFu + ((uy >> 16) & 1u)) & 0xFFFF0000u;
  return uy | ux;
}
__device__ inline unsigned short bf16_1(float x) {
  uint32_t u = __float_as_uint(x);
  return (unsigned short)((u + 0x7FFFu + ((u >> 16) & 1u)) >> 16);
}
__device__ inline float bf16_lo(uint32_t v) { return __uint_as_float(v << 16); }
__device__ inline float bf16_hi(uint32_t v) { return __uint_as_float(v & 0xFFFF0000u); }
__device__ inline float bf16_f(unsigned short h) { return __uint_as_float(((uint32_t)h) << 16); }

// zero cnt[NPAD], wsum[N]; thread (0,0) also computes softmax(att) -> wk
__global__ void init_kernel(int* __restrict__ cnt, float* __restrict__ wsum,
                            const float* __restrict__ att, float* __restrict__ wk) {
  int i = blockIdx.x * blockDim.x + threadIdx.x;
  if (i < NPAD) cnt[i] = 0;
  if (i < N) wsum[i] = 0.f;
  if (i == 0) {
    float mx = att[0];
    for (int j = 1; j < K + 1; ++j) mx = fmaxf(mx, att[j]);
    float ex[K + 1];
    float s = 0.f;
    for (int j = 0; j < K + 1; ++j) { ex[j] = expf(att[j] - mx); s += ex[j]; }
    for (int j = 0; j < K + 1; ++j) wk[j] = ex[j] / s;
  }
}

// W [Kdim][H] fp32 -> Wt [H][Kdim] bf16 (transposed)
__global__ void conv_wt_kernel(const float* __restrict__ W, unsigned short* __restrict__ Wt,
                               int Kdim) {
  int t = blockIdx.x * blockDim.x + threadIdx.x;
  int k8 = Kdim / 8;
  int n = t / k8;
  int kk = (t % k8) * 8;
  if (n >= H) return;
  float f[8];
#pragma unroll
  for (int j = 0; j < 8; ++j) f[j] = W[(size_t)(kk + j) * H + n];
  uint4 pk;
  pk.x = pack2_bf16(f[0], f[1]);
  pk.y = pack2_bf16(f[2], f[3]);
  pk.z = pack2_bf16(f[4], f[5]);
  pk.w = pack2_bf16(f[6], f[7]);
  *(uint4*)&Wt[(size_t)n * Kdim + kk] = pk;
}

// ---- bodies for the merged kernels ----

__device__ void fill_body(int bid, const int* __restrict__ row, const int* __restrict__ col,
                          const float* __restrict__ ew, int* __restrict__ cnt,
                          float* __restrict__ wsum, uint2* __restrict__ csr) {
  int i = bid * 256 + (int)threadIdx.x;
  if (i < E) {
    int s = row[i];
    float w = ew[i];
    atomicAdd(&wsum[s], w);
    int d = col[i];
    int old = atomicAdd(&cnt[d], 1);
    if (old < CAP) csr[(size_t)d * CAP + old] = make_uint2((uint32_t)s, __float_as_uint(w));
  }
}

__device__ void mlp1_body(int bid, const float* __restrict__ x,
                          const unsigned short* __restrict__ Wt1,
                          const float* __restrict__ b1, const float* __restrict__ g1,
                          const float* __restrict__ be1, const float* __restrict__ m1,
                          const float* __restrict__ v1, unsigned short* __restrict__ h1bf) {
  int wave = threadIdx.x >> 6;
  int lane = threadIdx.x & 63;
  int m_base = bid * 64 + wave * 16;
  int idx16 = lane & 15;
  int quad = lane >> 4;
  int m = m_base + idx16;
  bf16x8 afrag[8];
  if (m < N) {
    const float* xrow = x + (size_t)m * IN + quad * 8;
#pragma unroll
    for (int k0 = 0; k0 < 8; ++k0) {
      float4 a = *(const float4*)(xrow + k0 * 32);
      float4 b = *(const float4*)(xrow + k0 * 32 + 4);
      uint4 pk;
      pk.x = pack2_bf16(a.x, a.y);
      pk.y = pack2_bf16(a.z, a.w);
      pk.z = pack2_bf16(b.x, b.y);
      pk.w = pack2_bf16(b.z, b.w);
      afrag[k0] = *(bf16x8*)&pk;
    }
  } else {
    uint4 z = {0, 0, 0, 0};
#pragma unroll
    for (int k0 = 0; k0 < 8; ++k0) afrag[k0] = *(bf16x8*)&z;
  }
#pragma unroll
  for (int n0 = 0; n0 < 8; ++n0) {
    f32x4 acc = {0.f, 0.f, 0.f, 0.f};
    const unsigned short* wrow = Wt1 + (size_t)(n0 * 16 + idx16) * IN + quad * 8;
#pragma unroll
    for (int k0 = 0; k0 < 8; ++k0) {
      bf16x8 bfrag = *(const bf16x8*)(wrow + k0 * 32);
      acc = __builtin_amdgcn_mfma_f32_16x16x32_bf16(afrag[k0], bfrag, acc, 0, 0, 0);
    }
    int n = n0 * 16 + idx16;
    float sc = g1[n] * rsqrtf(v1[n] + EPS);
    float ad = b1[n] - m1[n];
    float bb = be1[n];
#pragma unroll
    for (int r = 0; r < 4; ++r) {
      int mm = m_base + quad * 4 + r;
      float val = fmaxf((acc[r] + ad) * sc + bb, 0.f);
      h1bf[(size_t)mm * H + n] = bf16_1(val);
    }
  }
}

// Merged: blocks [0,FILL_BLOCKS) build the CSR; the rest run mlp1 (independent),
// hiding the MLP inside fill's atomic-latency idle time.
__global__ __launch_bounds__(256) void fill_mlp1_kernel(
    const int* __restrict__ row, const int* __restrict__ col, const float* __restrict__ ew,
    int* __restrict__ cnt, float* __restrict__ wsum, uint2* __restrict__ csr,
    const float* __restrict__ x, const unsigned short* __restrict__ Wt1,
    const float* __restrict__ b1, const float* __restrict__ g1,
    const float* __restrict__ be1, const float* __restrict__ m1,
    const float* __restrict__ v1, unsigned short* __restrict__ h1bf) {
  if ((int)blockIdx.x < FILL_BLOCKS)
    fill_body(blockIdx.x, row, col, ew, cnt, wsum, csr);
  else
    mlp1_body(blockIdx.x - FILL_BLOCKS, x, Wt1, b1, g1, be1, m1, v1, h1bf);
}

// One wave per node: normalize w /= max(wsum,1), sort entries by src quartile
// (ballot-compact), write back + cumulative bucket counts (uchar4 in a uint).
__device__ void norm_body(int bid, const int* __restrict__ cnt, const float* __restrict__ wsum,
                          uint2* __restrict__ csr, uint32_t* __restrict__ meta) {
  int wave = threadIdx.x >> 6;
  int lane = threadIdx.x & 63;
  int node = bid * 4 + wave;
  if (node >= NPAD) return;
  if (node >= N) {
    if (lane == 0) meta[node] = 0;
    return;
  }
  int deg = min(cnt[node], CAP);
  size_t base = (size_t)node * CAP;
  bool act = lane < deg;
  uint2 e = make_uint2(0u, 0u);
  float w = 0.f;
  int b = 4;
  if (act) {
    e = csr[base + lane];
    w = __uint_as_float(e.y) / fmaxf(wsum[e.x], 1.0f);
    int s = (int)e.x;
    b = (s >= Q1) + (s >= Q2) + (s >= Q3);
  }
  unsigned long long below = (lane == 63) ? ~0ull >> 1 : ((1ull << lane) - 1ull);
  // lane 63: (1<<63)-1 works too but avoid UB-ish shifts; mask of lanes below 63:
  below = (1ull << lane) - 1ull;   // lane<64, 1ull<<63 defined; -1 gives low 63 bits
  int cum = 0;
  int pos = 0;
  uint32_t mv = 0;
#pragma unroll
  for (int bb = 0; bb < 4; ++bb) {
    unsigned long long m = __ballot(act && b == bb);
    if (act && b == bb) pos = cum + (int)__popcll(m & below);
    cum += (int)__popcll(m);
    mv |= ((uint32_t)cum) << (8 * bb);
  }
  if (act) csr[base + pos] = make_uint2(e.x, __float_as_uint(w));
  if (lane == 0) meta[node] = mv;
}

__device__ void mlp2_body(int bid, const unsigned short* __restrict__ h1bf,
                          const unsigned short* __restrict__ Wt2,
                          const float* __restrict__ b2, const float* __restrict__ g2,
                          const float* __restrict__ be2, const float* __restrict__ m2,
                          const float* __restrict__ v2, unsigned short* __restrict__ h0bf,
                          float* __restrict__ fused, const float* __restrict__ wk) {
  int wave = threadIdx.x >> 6;
  int lane = threadIdx.x & 63;
  int m_base = bid * 64 + wave * 16;
  int idx16 = lane & 15;
  int quad = lane >> 4;
  bf16x8 afrag[4];
  const unsigned short* arow = h1bf + (size_t)(m_base + idx16) * H + quad * 8;
#pragma unroll
  for (int k0 = 0; k0 < 4; ++k0) afrag[k0] = *(const bf16x8*)(arow + k0 * 32);
  float w0 = wk[0];
#pragma unroll
  for (int n0 = 0; n0 < 8; ++n0) {
    f32x4 acc = {0.f, 0.f, 0.f, 0.f};
    const unsigned short* wrow = Wt2 + (size_t)(n0 * 16 + idx16) * H + quad * 8;
#pragma unroll
    for (int k0 = 0; k0 < 4; ++k0) {
      bf16x8 bfrag = *(const bf16x8*)(wrow + k0 * 32);
      acc = __builtin_amdgcn_mfma_f32_16x16x32_bf16(afrag[k0], bfrag, acc, 0, 0, 0);
    }
    int n = n0 * 16 + idx16;
    float sc = g2[n] * rsqrtf(v2[n] + EPS);
    float ad = b2[n] - m2[n];
    float bb = be2[n];
#pragma unroll
    for (int r = 0; r < 4; ++r) {
      int m = m_base + quad * 4 + r;
      if (m < N) {
        float idv = bf16_f(h1bf[(size_t)m * H + n]);
        float val = fmaxf((acc[r] + ad) * sc + bb, 0.f) + idv;
        h0bf[(size_t)m * H + n] = bf16_1(val);
        fused[(size_t)m * H + n] = w0 * val;
      }
    }
  }
}

__global__ __launch_bounds__(256) void norm_mlp2_kernel(
    const int* __restrict__ cnt, const float* __restrict__ wsum,
    uint2* __restrict__ csr, uint32_t* __restrict__ meta,
    const unsigned short* __restrict__ h1bf, const unsigned short* __restrict__ Wt2,
    const float* __restrict__ b2, const float* __restrict__ g2,
    const float* __restrict__ be2, const float* __restrict__ m2,
    const float* __restrict__ v2, unsigned short* __restrict__ h0bf,
    float* __restrict__ fused, const float* __restrict__ wk) {
  if ((int)blockIdx.x < NORM_BLOCKS)
    norm_body(blockIdx.x, cnt, wsum, csr, meta);
  else
    mlp2_body(blockIdx.x - NORM_BLOCKS, h1bf, Wt2, b2, g2, be2, m2, v2, h0bf, fused, wk);
}

// Chunked APPNP SpMV: co-resident grid (1024 blocks = 4/CU), NPW=13 nodes/wave,
// src-quartile-sorted lists processed chunk-major so all waves sweep the same
// 3.2MB src window together -> gathers hit XCD-local L2. Half-wave per edge
// (32 lanes x 8B = 256B row, 2 edges per gather instruction).
__global__ __launch_bounds__(256, 4) void prop_kernel(
    const unsigned short* __restrict__ hk, const unsigned short* __restrict__ h0,
    unsigned short* __restrict__ outb,
    const uint32_t* __restrict__ meta, const uint2* __restrict__ csr,
    float* __restrict__ fused, const float* __restrict__ wk, int wj) {
  int wave = threadIdx.x >> 6;
  int lane = threadIdx.x & 63;
  int half = lane >> 5;
  int hl = lane & 31;
  int gwave = blockIdx.x * 4 + wave;
  int base_node = gwave * NPW;
  float acc[NPW][4];
#pragma unroll
  for (int nn = 0; nn < NPW; ++nn)
#pragma unroll
    for (int j = 0; j < 4; ++j) acc[nn][j] = 0.f;
  uint32_t mv[NPW];
#pragma unroll
  for (int nn = 0; nn < NPW; ++nn) {
    int node = base_node + nn;
    mv[nn] = (node < NPAD) ? meta[node] : 0u;
  }
#pragma unroll
  for (int c = 0; c < 4; ++c) {
#pragma unroll
    for (int nn = 0; nn < NPW; ++nn) {
      int node = base_node + nn;
      if (node >= NPAD) continue;
      int st = (c == 0) ? 0 : (int)((mv[nn] >> (8 * (c - 1))) & 255u);
      int en = (int)((mv[nn] >> (8 * c)) & 255u);
      size_t mbase = (size_t)node * CAP;
      int ng = (en - st + 1) >> 1;
      for (int g = 0; g < ng; ++g) {
        int e = st + g * 2 + half;
        bool v = e < en;
        uint2 ce = csr[mbase + (v ? e : st)];
        float w = v ? __uint_as_float(ce.y) : 0.f;
        uint2 rv = *(const uint2*)&hk[(size_t)ce.x * H + hl * 4];
        acc[nn][0] += w * bf16_lo(rv.x);
        acc[nn][1] += w * bf16_hi(rv.x);
        acc[nn][2] += w * bf16_lo(rv.y);
        acc[nn][3] += w * bf16_hi(rv.y);
      }
    }
    __syncthreads();   // keep the block's 4 waves phase-aligned per chunk
  }
  float wj_w = (wj >= 0) ? wk[wj] : 0.f;
#pragma unroll
  for (int nn = 0; nn < NPW; ++nn) {
    int node = base_node + nn;
    if (node >= N) continue;
    float a[4];
#pragma unroll
    for (int j = 0; j < 4; ++j) {
      a[j] = acc[nn][j] + __shfl_xor(acc[nn][j], 32, 64);
    }
    size_t idx = (size_t)node * H + hl * 4;
    uint2 hv = *(const uint2*)&h0[idx];
    float v0 = (1.f - ALPHA) * a[0] + ALPHA * bf16_lo(hv.x);
    float v1 = (1.f - ALPHA) * a[1] + ALPHA * bf16_hi(hv.x);
    float v2 = (1.f - ALPHA) * a[2] + ALPHA * bf16_lo(hv.y);
    float v3 = (1.f - ALPHA) * a[3] + ALPHA * bf16_hi(hv.y);
    if (half == 0) {
      uint2 pk;
      pk.x = pack2_bf16(v0, v1);
      pk.y = pack2_bf16(v2, v3);
      *(uint2*)&outb[idx] = pk;
    } else if (wj >= 0) {
      float4 f = *(float4*)&fused[idx];
      f.x += wj_w * v0;
      f.y += wj_w * v1;
      f.z += wj_w * v2;
      f.w += wj_w * v3;
      *(float4*)&fused[idx] = f;
    }
  }
}

// hid = relu(bn3(fused @ W3 + b3)); out = hid @ W4 + b4
__global__ __launch_bounds__(64) void head_kernel(
    const float* __restrict__ fused, const float* __restrict__ W3,
    const float* __restrict__ b3, const float* __restrict__ g3,
    const float* __restrict__ be3, const float* __restrict__ m3,
    const float* __restrict__ v3, const float* __restrict__ W4,
    const float* __restrict__ b4, float* __restrict__ out) {
  __shared__ float fl[16][H];
  __shared__ float hl[16][H2v];
  int node0 = blockIdx.x * 16;
  int t = threadIdx.x;
  for (int idx = t * 4; idx < 16 * H; idx += 64 * 4) {
    int r = idx >> 7, c = idx & (H - 1);
    *(float4*)&fl[r][c] = *(const float4*)&fused[(size_t)(node0 + r) * H + c];
  }
  __syncthreads();
  {
    int ng = t >> 4;
    int c0 = (t & 15) * 4;
    float acc[4][4];
#pragma unroll
    for (int a = 0; a < 4; ++a)
#pragma unroll
      for (int b = 0; b < 4; ++b) acc[a][b] = 0.f;
    for (int k = 0; k < H; k += 4) {
      float4 xv[4];
#pragma unroll
      for (int a = 0; a < 4; ++a) xv[a] = *(const float4*)&fl[ng * 4 + a][k];
      float4 wv[4];
#pragma unroll
      for (int j = 0; j < 4; ++j) wv[j] = *(const float4*)&W3[(size_t)(k + j) * H2v + c0];
#pragma unroll
      for (int a = 0; a < 4; ++a) {
        float xa0 = xv[a].x, xa1 = xv[a].y, xa2 = xv[a].z, xa3 = xv[a].w;
        acc[a][0] += xa0 * wv[0].x + xa1 * wv[1].x + xa2 * wv[2].x + xa3 * wv[3].x;
        acc[a][1] += xa0 * wv[0].y + xa1 * wv[1].y + xa2 * wv[2].y + xa3 * wv[3].y;
        acc[a][2] += xa0 * wv[0].z + xa1 * wv[1].z + xa2 * wv[2].z + xa3 * wv[3].z;
        acc[a][3] += xa0 * wv[0].w + xa1 * wv[1].w + xa2 * wv[2].w + xa3 * wv[3].w;
      }
    }
    float sc[4], ad[4], bb[4];
#pragma unroll
    for (int b = 0; b < 4; ++b) {
      int c = c0 + b;
      sc[b] = g3[c] * rsqrtf(v3[c] + EPS);
      ad[b] = b3[c] - m3[c];
      bb[b] = be3[c];
    }
#pragma unroll
    for (int a = 0; a < 4; ++a)
#pragma unroll
      for (int b = 0; b < 4; ++b)
        hl[ng * 4 + a][c0 + b] = fmaxf((acc[a][b] + ad[b]) * sc[b] + bb[b], 0.f);
  }
  __syncthreads();
  {
    int co = t & 31;
    int nh = t >> 5;
    float bias = b4[co];
#pragma unroll
    for (int a = 0; a < 8; ++a) {
      int nloc = nh * 8 + a;
      float accf = bias;
      for (int k = 0; k < H2v; k += 4) {
        float4 hv = *(const float4*)&hl[nloc][k];
        accf += hv.x * W4[(size_t)(k + 0) * O + co];
        accf += hv.y * W4[(size_t)(k + 1) * O + co];
        accf += hv.z * W4[(size_t)(k + 2) * O + co];
        accf += hv.w * W4[(size_t)(k + 3) * O + co];
      }
      out[(size_t)(node0 + nloc) * O + co] = accf;
    }
  }
}

}  // namespace

extern "C" void kernel_launch(void* const* d_in, const int* in_sizes, int n_in,
                              void* d_out, int out_size, void* d_ws, size_t ws_size,
                              hipStream_t stream) {
  const float* x   = (const float*)d_in[0];
  const int*   ei  = (const int*)d_in[1];
  const float* ew  = (const float*)d_in[2];
  const float* W1  = (const float*)d_in[3];
  const float* b1  = (const float*)d_in[4];
  const float* g1  = (const float*)d_in[5];
  const float* be1 = (const float*)d_in[6];
  const float* m1  = (const float*)d_in[7];
  const float* v1  = (const float*)d_in[8];
  const float* W2  = (const float*)d_in[9];
  const float* b2  = (const float*)d_in[10];
  const float* g2  = (const float*)d_in[11];
  const float* be2 = (const float*)d_in[12];
  const float* m2  = (const float*)d_in[13];
  const float* v2  = (const float*)d_in[14];
  const float* att = (const float*)d_in[15];
  const float* W3  = (const float*)d_in[16];
  const float* b3  = (const float*)d_in[17];
  const float* g3  = (const float*)d_in[18];
  const float* be3 = (const float*)d_in[19];
  const float* m3  = (const float*)d_in[20];
  const float* v3  = (const float*)d_in[21];
  const float* W4  = (const float*)d_in[22];
  const float* b4  = (const float*)d_in[23];
  const int* row = ei;
  const int* col = ei + E;
  float* out = (float*)d_out;

  char* p = (char*)d_ws;
  auto carve = [&](size_t bytes) -> void* {
    void* q = (void*)p;
    p += (bytes + 255) & ~(size_t)255;
    return q;
  };
  int*      cnt  = (int*)carve((size_t)NPAD * 4);
  float*    wsum = (float*)carve((size_t)N * 4);
  uint32_t* meta = (uint32_t*)carve((size_t)NPAD * 4);
  uint2*    csr  = (uint2*)carve((size_t)N * CAP * 8);
  float*    wk   = (float*)carve(64);
  unsigned short* Wt1  = (unsigned short*)carve((size_t)H * IN * 2);
  unsigned short* Wt2  = (unsigned short*)carve((size_t)H * H * 2);
  unsigned short* h1bf = (unsigned short*)carve((size_t)NPAD * H * 2);
  unsigned short* bf0  = (unsigned short*)carve((size_t)NPAD * H * 2);
  unsigned short* bfA  = (unsigned short*)carve((size_t)NPAD * H * 2);
  unsigned short* bfB  = (unsigned short*)carve((size_t)NPAD * H * 2);
  float* fused = (float*)carve((size_t)N * H * 4);

  const int tb = 256;
  init_kernel<<<(NPAD + tb - 1) / tb, tb, 0, stream>>>(cnt, wsum, att, wk);
  conv_wt_kernel<<<(H * (IN / 8) + tb - 1) / tb, tb, 0, stream>>>(W1, Wt1, IN);
  conv_wt_kernel<<<(H * (H / 8) + tb - 1) / tb, tb, 0, stream>>>(W2, Wt2, H);

  fill_mlp1_kernel<<<FILL_BLOCKS + MLP_BLOCKS, 256, 0, stream>>>(
      row, col, ew, cnt, wsum, csr, x, Wt1, b1, g1, be1, m1, v1, h1bf);
  norm_mlp2_kernel<<<NORM_BLOCKS + MLP_BLOCKS, 256, 0, stream>>>(
      cnt, wsum, csr, meta, h1bf, Wt2, b2, g2, be2, m2, v2, bf0, fused, wk);

  // APPNP propagation: 5 outer x 5 inner; 3 rotating bf16 buffers.
  unsigned short* h0 = bf0;
  unsigned short* pa = bfA;
  unsigned short* pb = bfB;
  for (int j = 1; j <= K; ++j) {
    const unsigned short* src = h0;
    unsigned short* dst = pa;
    for (int i = 0; i < K; ++i) {
      int wj = (i == K - 1) ? j : -1;
      prop_kernel<<<PROP_BLOCKS, 256, 0, stream>>>(src, h0, dst, meta, csr, fused, wk, wj);
      if (i < K - 1) {
        src = dst;
        dst = (dst == pa) ? pb : pa;
      }
    }
    unsigned short* oldh0 = h0;
    h0 = pa;
    pa = pb;
    pb = oldh0;
  }

  head_kernel<<<N / 16, 64, 0, stream>>>(fused, W3, b3, g3, be3, m3, v3, W4, b4, out);
}

// Round 9
// 2294.176 us; speedup vs baseline: 1.1897x; 1.1897x over previous
//
#include <hip/hip_runtime.h>
#include <cstddef>
#include <cstdint>

namespace {

constexpr int N   = 50000;
constexpr int E   = 800000;
constexpr int IN  = 256;
constexpr int H   = 128;
constexpr int H2v = 64;
constexpr int O   = 32;
constexpr int K   = 5;
constexpr float ALPHA = 0.1f;
constexpr float EPS   = 1e-5f;
constexpr int NPAD = 50048;
constexpr int CAP  = 48;             // fixed CSR capacity per node (deg~Poisson(16))
constexpr int Q1 = 12500, Q2 = 25000, Q3 = 37500;   // src quartiles
constexpr int NPW = 8;               // nodes per wave in prop
constexpr int PROP_BLOCKS = NPAD / (4 * NPW);       // 1564
constexpr int NORM_BLOCKS = NPAD / 4;               // 12512
constexpr int MLP_BLOCKS  = NPAD / 64;              // 782

typedef __bf16 bf16x8 __attribute__((ext_vector_type(8)));
typedef float  f32x4  __attribute__((ext_vector_type(4)));

__device__ inline uint32_t pack2_bf16(float x, float y) {
  uint32_t ux = __float_as_uint(x);
  uint32_t uy = __float_as_uint(y);
  ux = (ux + 0x7FFFu + ((ux >> 16) & 1u)) >> 16;
  uy = (uy + 0x7FFFu + ((uy >> 16) & 1u)) & 0xFFFF0000u;
  return uy | ux;
}
__device__ inline unsigned short bf16_1(float x) {
  uint32_t u = __float_as_uint(x);
  return (unsigned short)((u + 0x7FFFu + ((u >> 16) & 1u)) >> 16);
}
__device__ inline float bf16_lo(uint32_t v) { return __uint_as_float(v << 16); }
__device__ inline float bf16_hi(uint32_t v) { return __uint_as_float(v & 0xFFFF0000u); }
__device__ inline float bf16_f(unsigned short h) { return __uint_as_float(((uint32_t)h) << 16); }

// zero cnt[NPAD], wsum[N]; thread 0 computes softmax(att) -> wk
__global__ void init_kernel(int* __restrict__ cnt, float* __restrict__ wsum,
                            const float* __restrict__ att, float* __restrict__ wk) {
  int i = blockIdx.x * blockDim.x + threadIdx.x;
  if (i < NPAD) cnt[i] = 0;
  if (i < N) wsum[i] = 0.f;
  if (i == 0) {
    float mx = att[0];
    for (int j = 1; j < K + 1; ++j) mx = fmaxf(mx, att[j]);
    float ex[K + 1];
    float s = 0.f;
    for (int j = 0; j < K + 1; ++j) { ex[j] = expf(att[j] - mx); s += ex[j]; }
    for (int j = 0; j < K + 1; ++j) wk[j] = ex[j] / s;
  }
}

// Standalone fill: VGPR=8 keeps occupancy high -> max outstanding atomics.
__global__ void fused_fill_kernel(const int* __restrict__ row, const int* __restrict__ col,
                                  const float* __restrict__ ew,
                                  int* __restrict__ cnt, float* __restrict__ wsum,
                                  uint2* __restrict__ csr) {
  int i = blockIdx.x * blockDim.x + threadIdx.x;
  if (i < E) {
    int s = row[i];
    float w = ew[i];
    atomicAdd(&wsum[s], w);
    int d = col[i];
    int old = atomicAdd(&cnt[d], 1);
    if (old < CAP) csr[(size_t)d * CAP + old] = make_uint2((uint32_t)s, __float_as_uint(w));
  }
}

// W [Kdim][H] fp32 -> Wt [H][Kdim] bf16 (transposed)
__global__ void conv_wt_kernel(const float* __restrict__ W, unsigned short* __restrict__ Wt,
                               int Kdim) {
  int t = blockIdx.x * blockDim.x + threadIdx.x;
  int k8 = Kdim / 8;
  int n = t / k8;
  int kk = (t % k8) * 8;
  if (n >= H) return;
  float f[8];
#pragma unroll
  for (int j = 0; j < 8; ++j) f[j] = W[(size_t)(kk + j) * H + n];
  uint4 pk;
  pk.x = pack2_bf16(f[0], f[1]);
  pk.y = pack2_bf16(f[2], f[3]);
  pk.z = pack2_bf16(f[4], f[5]);
  pk.w = pack2_bf16(f[6], f[7]);
  *(uint4*)&Wt[(size_t)n * Kdim + kk] = pk;
}

// h1 = relu(bn1(x @ W1 + b1)) via MFMA; x read fp32, packed to bf16 in-register.
__global__ __launch_bounds__(256) void mlp1_mfma_kernel(
    const float* __restrict__ x, const unsigned short* __restrict__ Wt1,
    const float* __restrict__ b1, const float* __restrict__ g1,
    const float* __restrict__ be1, const float* __restrict__ m1,
    const float* __restrict__ v1, unsigned short* __restrict__ h1bf) {
  int wave = threadIdx.x >> 6;
  int lane = threadIdx.x & 63;
  int m_base = blockIdx.x * 64 + wave * 16;
  int idx16 = lane & 15;
  int quad = lane >> 4;
  int m = m_base + idx16;
  bf16x8 afrag[8];
  if (m < N) {
    const float* xrow = x + (size_t)m * IN + quad * 8;
#pragma unroll
    for (int k0 = 0; k0 < 8; ++k0) {
      float4 a = *(const float4*)(xrow + k0 * 32);
      float4 b = *(const float4*)(xrow + k0 * 32 + 4);
      uint4 pk;
      pk.x = pack2_bf16(a.x, a.y);
      pk.y = pack2_bf16(a.z, a.w);
      pk.z = pack2_bf16(b.x, b.y);
      pk.w = pack2_bf16(b.z, b.w);
      afrag[k0] = *(bf16x8*)&pk;
    }
  } else {
    uint4 z = {0, 0, 0, 0};
#pragma unroll
    for (int k0 = 0; k0 < 8; ++k0) afrag[k0] = *(bf16x8*)&z;
  }
#pragma unroll
  for (int n0 = 0; n0 < 8; ++n0) {
    f32x4 acc = {0.f, 0.f, 0.f, 0.f};
    const unsigned short* wrow = Wt1 + (size_t)(n0 * 16 + idx16) * IN + quad * 8;
#pragma unroll
    for (int k0 = 0; k0 < 8; ++k0) {
      bf16x8 bfrag = *(const bf16x8*)(wrow + k0 * 32);
      acc = __builtin_amdgcn_mfma_f32_16x16x32_bf16(afrag[k0], bfrag, acc, 0, 0, 0);
    }
    int n = n0 * 16 + idx16;
    float sc = g1[n] * rsqrtf(v1[n] + EPS);
    float ad = b1[n] - m1[n];
    float bb = be1[n];
#pragma unroll
    for (int r = 0; r < 4; ++r) {
      int mm = m_base + quad * 4 + r;
      float val = fmaxf((acc[r] + ad) * sc + bb, 0.f);
      h1bf[(size_t)mm * H + n] = bf16_1(val);
    }
  }
}

// One wave per node: normalize w /= max(wsum,1), sort entries by src quartile
// (ballot-compact), write back + cumulative bucket counts (4x8-bit in a uint).
__device__ void norm_body(int bid, const int* __restrict__ cnt, const float* __restrict__ wsum,
                          uint2* __restrict__ csr, uint32_t* __restrict__ meta) {
  int wave = threadIdx.x >> 6;
  int lane = threadIdx.x & 63;
  int node = bid * 4 + wave;
  if (node >= NPAD) return;
  if (node >= N) {
    if (lane == 0) meta[node] = 0;
    return;
  }
  int deg = min(cnt[node], CAP);
  size_t base = (size_t)node * CAP;
  bool act = lane < deg;
  uint2 e = make_uint2(0u, 0u);
  float w = 0.f;
  int b = 4;
  if (act) {
    e = csr[base + lane];
    w = __uint_as_float(e.y) / fmaxf(wsum[e.x], 1.0f);
    int s = (int)e.x;
    b = (s >= Q1) + (s >= Q2) + (s >= Q3);
  }
  unsigned long long below = (1ull << lane) - 1ull;
  int cum = 0;
  int pos = 0;
  uint32_t mv = 0;
#pragma unroll
  for (int bb = 0; bb < 4; ++bb) {
    unsigned long long m = __ballot(act && b == bb);
    if (act && b == bb) pos = cum + (int)__popcll(m & below);
    cum += (int)__popcll(m);
    mv |= ((uint32_t)cum) << (8 * bb);
  }
  if (act) csr[base + pos] = make_uint2(e.x, __float_as_uint(w));
  if (lane == 0) meta[node] = mv;
}

__device__ void mlp2_body(int bid, const unsigned short* __restrict__ h1bf,
                          const unsigned short* __restrict__ Wt2,
                          const float* __restrict__ b2, const float* __restrict__ g2,
                          const float* __restrict__ be2, const float* __restrict__ m2,
                          const float* __restrict__ v2, unsigned short* __restrict__ h0bf,
                          float* __restrict__ fused, const float* __restrict__ wk) {
  int wave = threadIdx.x >> 6;
  int lane = threadIdx.x & 63;
  int m_base = bid * 64 + wave * 16;
  int idx16 = lane & 15;
  int quad = lane >> 4;
  bf16x8 afrag[4];
  const unsigned short* arow = h1bf + (size_t)(m_base + idx16) * H + quad * 8;
#pragma unroll
  for (int k0 = 0; k0 < 4; ++k0) afrag[k0] = *(const bf16x8*)(arow + k0 * 32);
  float w0 = wk[0];
#pragma unroll
  for (int n0 = 0; n0 < 8; ++n0) {
    f32x4 acc = {0.f, 0.f, 0.f, 0.f};
    const unsigned short* wrow = Wt2 + (size_t)(n0 * 16 + idx16) * H + quad * 8;
#pragma unroll
    for (int k0 = 0; k0 < 4; ++k0) {
      bf16x8 bfrag = *(const bf16x8*)(wrow + k0 * 32);
      acc = __builtin_amdgcn_mfma_f32_16x16x32_bf16(afrag[k0], bfrag, acc, 0, 0, 0);
    }
    int n = n0 * 16 + idx16;
    float sc = g2[n] * rsqrtf(v2[n] + EPS);
    float ad = b2[n] - m2[n];
    float bb = be2[n];
#pragma unroll
    for (int r = 0; r < 4; ++r) {
      int m = m_base + quad * 4 + r;
      if (m < N) {
        float idv = bf16_f(h1bf[(size_t)m * H + n]);
        float val = fmaxf((acc[r] + ad) * sc + bb, 0.f) + idv;
        h0bf[(size_t)m * H + n] = bf16_1(val);
        fused[(size_t)m * H + n] = w0 * val;
      }
    }
  }
}

__global__ __launch_bounds__(256) void norm_mlp2_kernel(
    const int* __restrict__ cnt, const float* __restrict__ wsum,
    uint2* __restrict__ csr, uint32_t* __restrict__ meta,
    const unsigned short* __restrict__ h1bf, const unsigned short* __restrict__ Wt2,
    const float* __restrict__ b2, const float* __restrict__ g2,
    const float* __restrict__ be2, const float* __restrict__ m2,
    const float* __restrict__ v2, unsigned short* __restrict__ h0bf,
    float* __restrict__ fused, const float* __restrict__ wk) {
  if ((int)blockIdx.x < NORM_BLOCKS)
    norm_body(blockIdx.x, cnt, wsum, csr, meta);
  else
    mlp2_body(blockIdx.x - NORM_BLOCKS, h1bf, Wt2, b2, g2, be2, m2, v2, h0bf, fused, wk);
}

// APPNP SpMV with R7 gather geometry (quarter-wave: 16 lanes x uint4 = 256B row,
// 4 edges/instruction) but edge lists swept in src-quartile chunks so the whole
// machine touches a 3.2MB src window at a time (fits per-XCD L2). NPW=8 nodes
// unrolled per wave keeps ~8 gathers in flight. No barriers.
__global__ __launch_bounds__(256) void prop_kernel(
    const unsigned short* __restrict__ hk, const unsigned short* __restrict__ h0,
    unsigned short* __restrict__ outb,
    const uint32_t* __restrict__ meta, const uint2* __restrict__ csr,
    float* __restrict__ fused, const float* __restrict__ wk, int wj) {
  int wave = threadIdx.x >> 6;
  int lane = threadIdx.x & 63;
  int quarter = lane >> 4;
  int colb = (lane & 15) * 8;
  int node0 = (blockIdx.x * 4 + wave) * NPW;
  float acc[NPW][8];
#pragma unroll
  for (int nn = 0; nn < NPW; ++nn)
#pragma unroll
    for (int j = 0; j < 8; ++j) acc[nn][j] = 0.f;
  uint32_t mv[NPW];
#pragma unroll
  for (int nn = 0; nn < NPW; ++nn) mv[nn] = meta[node0 + nn];
#pragma unroll
  for (int c = 0; c < 4; ++c) {
#pragma unroll
    for (int nn = 0; nn < NPW; ++nn) {
      int st = (c == 0) ? 0 : (int)((mv[nn] >> (8 * (c - 1))) & 255u);
      int en = (int)((mv[nn] >> (8 * c)) & 255u);
      size_t base = (size_t)(node0 + nn) * CAP;
      for (int e0 = st; e0 < en; e0 += 4) {
        int e = e0 + quarter;
        bool v = e < en;
        uint2 ce = csr[base + (v ? e : st)];
        float w = v ? __uint_as_float(ce.y) : 0.f;
        uint4 rv = *(const uint4*)&hk[(size_t)ce.x * H + colb];
        acc[nn][0] += w * bf16_lo(rv.x); acc[nn][1] += w * bf16_hi(rv.x);
        acc[nn][2] += w * bf16_lo(rv.y); acc[nn][3] += w * bf16_hi(rv.y);
        acc[nn][4] += w * bf16_lo(rv.z); acc[nn][5] += w * bf16_hi(rv.z);
        acc[nn][6] += w * bf16_lo(rv.w); acc[nn][7] += w * bf16_hi(rv.w);
      }
    }
  }
  float wj_w = (wj >= 0) ? wk[wj] : 0.f;
#pragma unroll
  for (int nn = 0; nn < NPW; ++nn) {
    int node = node0 + nn;
    if (node >= N) continue;
    float a[8];
#pragma unroll
    for (int j = 0; j < 8; ++j) {
      float t = acc[nn][j] + __shfl_xor(acc[nn][j], 16, 64);
      a[j] = t + __shfl_xor(t, 32, 64);
    }
    size_t idx = (size_t)node * H + colb;
    if (quarter == 0) {
      uint4 hv = *(const uint4*)&h0[idx];
      float v0 = (1.f - ALPHA) * a[0] + ALPHA * bf16_lo(hv.x);
      float v1 = (1.f - ALPHA) * a[1] + ALPHA * bf16_hi(hv.x);
      float v2 = (1.f - ALPHA) * a[2] + ALPHA * bf16_lo(hv.y);
      float v3 = (1.f - ALPHA) * a[3] + ALPHA * bf16_hi(hv.y);
      float v4 = (1.f - ALPHA) * a[4] + ALPHA * bf16_lo(hv.z);
      float v5 = (1.f - ALPHA) * a[5] + ALPHA * bf16_hi(hv.z);
      float v6 = (1.f - ALPHA) * a[6] + ALPHA * bf16_lo(hv.w);
      float v7 = (1.f - ALPHA) * a[7] + ALPHA * bf16_hi(hv.w);
      uint4 pk;
      pk.x = pack2_bf16(v0, v1);
      pk.y = pack2_bf16(v2, v3);
      pk.z = pack2_bf16(v4, v5);
      pk.w = pack2_bf16(v6, v7);
      *(uint4*)&outb[idx] = pk;
    } else if (quarter == 1 && wj >= 0) {
      uint4 hv = *(const uint4*)&h0[idx];
      float v0 = (1.f - ALPHA) * a[0] + ALPHA * bf16_lo(hv.x);
      float v1 = (1.f - ALPHA) * a[1] + ALPHA * bf16_hi(hv.x);
      float v2 = (1.f - ALPHA) * a[2] + ALPHA * bf16_lo(hv.y);
      float v3 = (1.f - ALPHA) * a[3] + ALPHA * bf16_hi(hv.y);
      float v4 = (1.f - ALPHA) * a[4] + ALPHA * bf16_lo(hv.z);
      float v5 = (1.f - ALPHA) * a[5] + ALPHA * bf16_hi(hv.z);
      float v6 = (1.f - ALPHA) * a[6] + ALPHA * bf16_lo(hv.w);
      float v7 = (1.f - ALPHA) * a[7] + ALPHA * bf16_hi(hv.w);
      float4 f0 = *(float4*)&fused[idx];
      float4 f1 = *(float4*)&fused[idx + 4];
      f0.x += wj_w * v0; f0.y += wj_w * v1; f0.z += wj_w * v2; f0.w += wj_w * v3;
      f1.x += wj_w * v4; f1.y += wj_w * v5; f1.z += wj_w * v6; f1.w += wj_w * v7;
      *(float4*)&fused[idx] = f0;
      *(float4*)&fused[idx + 4] = f1;
    }
  }
}

// hid = relu(bn3(fused @ W3 + b3)); out = hid @ W4 + b4
__global__ __launch_bounds__(64) void head_kernel(
    const float* __restrict__ fused, const float* __restrict__ W3,
    const float* __restrict__ b3, const float* __restrict__ g3,
    const float* __restrict__ be3, const float* __restrict__ m3,
    const float* __restrict__ v3, const float* __restrict__ W4,
    const float* __restrict__ b4, float* __restrict__ out) {
  __shared__ float fl[16][H];
  __shared__ float hl[16][H2v];
  int node0 = blockIdx.x * 16;
  int t = threadIdx.x;
  for (int idx = t * 4; idx < 16 * H; idx += 64 * 4) {
    int r = idx >> 7, c = idx & (H - 1);
    *(float4*)&fl[r][c] = *(const float4*)&fused[(size_t)(node0 + r) * H + c];
  }
  __syncthreads();
  {
    int ng = t >> 4;
    int c0 = (t & 15) * 4;
    float acc[4][4];
#pragma unroll
    for (int a = 0; a < 4; ++a)
#pragma unroll
      for (int b = 0; b < 4; ++b) acc[a][b] = 0.f;
    for (int k = 0; k < H; k += 4) {
      float4 xv[4];
#pragma unroll
      for (int a = 0; a < 4; ++a) xv[a] = *(const float4*)&fl[ng * 4 + a][k];
      float4 wv[4];
#pragma unroll
      for (int j = 0; j < 4; ++j) wv[j] = *(const float4*)&W3[(size_t)(k + j) * H2v + c0];
#pragma unroll
      for (int a = 0; a < 4; ++a) {
        float xa0 = xv[a].x, xa1 = xv[a].y, xa2 = xv[a].z, xa3 = xv[a].w;
        acc[a][0] += xa0 * wv[0].x + xa1 * wv[1].x + xa2 * wv[2].x + xa3 * wv[3].x;
        acc[a][1] += xa0 * wv[0].y + xa1 * wv[1].y + xa2 * wv[2].y + xa3 * wv[3].y;
        acc[a][2] += xa0 * wv[0].z + xa1 * wv[1].z + xa2 * wv[2].z + xa3 * wv[3].z;
        acc[a][3] += xa0 * wv[0].w + xa1 * wv[1].w + xa2 * wv[2].w + xa3 * wv[3].w;
      }
    }
    float sc[4], ad[4], bb[4];
#pragma unroll
    for (int b = 0; b < 4; ++b) {
      int c = c0 + b;
      sc[b] = g3[c] * rsqrtf(v3[c] + EPS);
      ad[b] = b3[c] - m3[c];
      bb[b] = be3[c];
    }
#pragma unroll
    for (int a = 0; a < 4; ++a)
#pragma unroll
      for (int b = 0; b < 4; ++b)
        hl[ng * 4 + a][c0 + b] = fmaxf((acc[a][b] + ad[b]) * sc[b] + bb[b], 0.f);
  }
  __syncthreads();
  {
    int co = t & 31;
    int nh = t >> 5;
    float bias = b4[co];
#pragma unroll
    for (int a = 0; a < 8; ++a) {
      int nloc = nh * 8 + a;
      float accf = bias;
      for (int k = 0; k < H2v; k += 4) {
        float4 hv = *(const float4*)&hl[nloc][k];
        accf += hv.x * W4[(size_t)(k + 0) * O + co];
        accf += hv.y * W4[(size_t)(k + 1) * O + co];
        accf += hv.z * W4[(size_t)(k + 2) * O + co];
        accf += hv.w * W4[(size_t)(k + 3) * O + co];
      }
      out[(size_t)(node0 + nloc) * O + co] = accf;
    }
  }
}

}  // namespace

extern "C" void kernel_launch(void* const* d_in, const int* in_sizes, int n_in,
                              void* d_out, int out_size, void* d_ws, size_t ws_size,
                              hipStream_t stream) {
  const float* x   = (const float*)d_in[0];
  const int*   ei  = (const int*)d_in[1];
  const float* ew  = (const float*)d_in[2];
  const float* W1  = (const float*)d_in[3];
  const float* b1  = (const float*)d_in[4];
  const float* g1  = (const float*)d_in[5];
  const float* be1 = (const float*)d_in[6];
  const float* m1  = (const float*)d_in[7];
  const float* v1  = (const float*)d_in[8];
  const float* W2  = (const float*)d_in[9];
  const float* b2  = (const float*)d_in[10];
  const float* g2  = (const float*)d_in[11];
  const float* be2 = (const float*)d_in[12];
  const float* m2  = (const float*)d_in[13];
  const float* v2  = (const float*)d_in[14];
  const float* att = (const float*)d_in[15];
  const float* W3  = (const float*)d_in[16];
  const float* b3  = (const float*)d_in[17];
  const float* g3  = (const float*)d_in[18];
  const float* be3 = (const float*)d_in[19];
  const float* m3  = (const float*)d_in[20];
  const float* v3  = (const float*)d_in[21];
  const float* W4  = (const float*)d_in[22];
  const float* b4  = (const float*)d_in[23];
  const int* row = ei;
  const int* col = ei + E;
  float* out = (float*)d_out;

  char* p = (char*)d_ws;
  auto carve = [&](size_t bytes) -> void* {
    void* q = (void*)p;
    p += (bytes + 255) & ~(size_t)255;
    return q;
  };
  int*      cnt  = (int*)carve((size_t)NPAD * 4);
  float*    wsum = (float*)carve((size_t)N * 4);
  uint32_t* meta = (uint32_t*)carve((size_t)NPAD * 4);
  uint2*    csr  = (uint2*)carve((size_t)N * CAP * 8);
  float*    wk   = (float*)carve(64);
  unsigned short* Wt1  = (unsigned short*)carve((size_t)H * IN * 2);
  unsigned short* Wt2  = (unsigned short*)carve((size_t)H * H * 2);
  unsigned short* h1bf = (unsigned short*)carve((size_t)NPAD * H * 2);
  unsigned short* bf0  = (unsigned short*)carve((size_t)NPAD * H * 2);
  unsigned short* bfA  = (unsigned short*)carve((size_t)NPAD * H * 2);
  unsigned short* bfB  = (unsigned short*)carve((size_t)NPAD * H * 2);
  float* fused = (float*)carve((size_t)N * H * 4);

  const int tb = 256;
  init_kernel<<<(NPAD + tb - 1) / tb, tb, 0, stream>>>(cnt, wsum, att, wk);
  conv_wt_kernel<<<(H * (IN / 8) + tb - 1) / tb, tb, 0, stream>>>(W1, Wt1, IN);
  conv_wt_kernel<<<(H * (H / 8) + tb - 1) / tb, tb, 0, stream>>>(W2, Wt2, H);

  fused_fill_kernel<<<(E + tb - 1) / tb, tb, 0, stream>>>(row, col, ew, cnt, wsum, csr);
  mlp1_mfma_kernel<<<MLP_BLOCKS, 256, 0, stream>>>(x, Wt1, b1, g1, be1, m1, v1, h1bf);
  norm_mlp2_kernel<<<NORM_BLOCKS + MLP_BLOCKS, 256, 0, stream>>>(
      cnt, wsum, csr, meta, h1bf, Wt2, b2, g2, be2, m2, v2, bf0, fused, wk);

  // APPNP propagation: 5 outer x 5 inner; 3 rotating bf16 buffers.
  unsigned short* h0 = bf0;
  unsigned short* pa = bfA;
  unsigned short* pb = bfB;
  for (int j = 1; j <= K; ++j) {
    const unsigned short* src = h0;
    unsigned short* dst = pa;
    for (int i = 0; i < K; ++i) {
      int wj = (i == K - 1) ? j : -1;
      prop_kernel<<<PROP_BLOCKS, 256, 0, stream>>>(src, h0, dst, meta, csr, fused, wk, wj);
      if (i < K - 1) {
        src = dst;
        dst = (dst == pa) ? pb : pa;
      }
    }
    unsigned short* oldh0 = h0;
    h0 = pa;
    pa = pb;
    pb = oldh0;
  }

  head_kernel<<<N / 16, 64, 0, stream>>>(fused, W3, b3, g3, be3, m3, v3, W4, b4, out);
}

// Round 10
// 1222.359 us; speedup vs baseline: 2.2329x; 1.8768x over previous
//
#include <hip/hip_runtime.h>
#include <cstddef>
#include <cstdint>

namespace {

constexpr int N   = 50000;
constexpr int E   = 800000;
constexpr int IN  = 256;
constexpr int H   = 128;
constexpr int H2v = 64;
constexpr int O   = 32;
constexpr int K   = 5;
constexpr float ALPHA = 0.1f;
constexpr float EPS   = 1e-5f;
constexpr int NPAD = 50048;
constexpr int CAP  = 48;             // fixed CSR capacity per node (deg~Poisson(16))
constexpr int NPW  = 4;              // nodes per wave in prop
constexpr int PROP_BLOCKS = NPAD / (4 * NPW);       // 3128
constexpr int NORM_BLOCKS = NPAD / 4;               // 12512
constexpr int MLP_BLOCKS  = NPAD / 64;              // 782

typedef __bf16 bf16x8 __attribute__((ext_vector_type(8)));
typedef float  f32x4  __attribute__((ext_vector_type(4)));

__device__ inline uint32_t pack2_bf16(float x, float y) {
  uint32_t ux = __float_as_uint(x);
  uint32_t uy = __float_as_uint(y);
  ux = (ux + 0x7FFFu + ((ux >> 16) & 1u)) >> 16;
  uy = (uy + 0x7FFFu + ((uy >> 16) & 1u)) & 0xFFFF0000u;
  return uy | ux;
}
__device__ inline unsigned short bf16_1(float x) {
  uint32_t u = __float_as_uint(x);
  return (unsigned short)((u + 0x7FFFu + ((u >> 16) & 1u)) >> 16);
}
__device__ inline float bf16_lo(uint32_t v) { return __uint_as_float(v << 16); }
__device__ inline float bf16_hi(uint32_t v) { return __uint_as_float(v & 0xFFFF0000u); }
__device__ inline float bf16_f(unsigned short h) { return __uint_as_float(((uint32_t)h) << 16); }

// zero cnt[NPAD], wsum[N]; thread 0 computes softmax(att) -> wk
__global__ void init_kernel(int* __restrict__ cnt, float* __restrict__ wsum,
                            const float* __restrict__ att, float* __restrict__ wk) {
  int i = blockIdx.x * blockDim.x + threadIdx.x;
  if (i < NPAD) cnt[i] = 0;
  if (i < N) wsum[i] = 0.f;
  if (i == 0) {
    float mx = att[0];
    for (int j = 1; j < K + 1; ++j) mx = fmaxf(mx, att[j]);
    float ex[K + 1];
    float s = 0.f;
    for (int j = 0; j < K + 1; ++j) { ex[j] = expf(att[j] - mx); s += ex[j]; }
    for (int j = 0; j < K + 1; ++j) wk[j] = ex[j] / s;
  }
}

// Standalone fill: VGPR=8 keeps occupancy high -> max outstanding atomics.
__global__ void fused_fill_kernel(const int* __restrict__ row, const int* __restrict__ col,
                                  const float* __restrict__ ew,
                                  int* __restrict__ cnt, float* __restrict__ wsum,
                                  uint2* __restrict__ csr) {
  int i = blockIdx.x * blockDim.x + threadIdx.x;
  if (i < E) {
    int s = row[i];
    float w = ew[i];
    atomicAdd(&wsum[s], w);
    int d = col[i];
    int old = atomicAdd(&cnt[d], 1);
    if (old < CAP) csr[(size_t)d * CAP + old] = make_uint2((uint32_t)s, __float_as_uint(w));
  }
}

// W [Kdim][H] fp32 -> Wt [H][Kdim] bf16 (transposed)
__global__ void conv_wt_kernel(const float* __restrict__ W, unsigned short* __restrict__ Wt,
                               int Kdim) {
  int t = blockIdx.x * blockDim.x + threadIdx.x;
  int k8 = Kdim / 8;
  int n = t / k8;
  int kk = (t % k8) * 8;
  if (n >= H) return;
  float f[8];
#pragma unroll
  for (int j = 0; j < 8; ++j) f[j] = W[(size_t)(kk + j) * H + n];
  uint4 pk;
  pk.x = pack2_bf16(f[0], f[1]);
  pk.y = pack2_bf16(f[2], f[3]);
  pk.z = pack2_bf16(f[4], f[5]);
  pk.w = pack2_bf16(f[6], f[7]);
  *(uint4*)&Wt[(size_t)n * Kdim + kk] = pk;
}

// h1 = relu(bn1(x @ W1 + b1)) via MFMA; x read fp32, packed to bf16 in-register.
__global__ __launch_bounds__(256) void mlp1_mfma_kernel(
    const float* __restrict__ x, const unsigned short* __restrict__ Wt1,
    const float* __restrict__ b1, const float* __restrict__ g1,
    const float* __restrict__ be1, const float* __restrict__ m1,
    const float* __restrict__ v1, unsigned short* __restrict__ h1bf) {
  int wave = threadIdx.x >> 6;
  int lane = threadIdx.x & 63;
  int m_base = blockIdx.x * 64 + wave * 16;
  int idx16 = lane & 15;
  int quad = lane >> 4;
  int m = m_base + idx16;
  bf16x8 afrag[8];
  if (m < N) {
    const float* xrow = x + (size_t)m * IN + quad * 8;
#pragma unroll
    for (int k0 = 0; k0 < 8; ++k0) {
      float4 a = *(const float4*)(xrow + k0 * 32);
      float4 b = *(const float4*)(xrow + k0 * 32 + 4);
      uint4 pk;
      pk.x = pack2_bf16(a.x, a.y);
      pk.y = pack2_bf16(a.z, a.w);
      pk.z = pack2_bf16(b.x, b.y);
      pk.w = pack2_bf16(b.z, b.w);
      afrag[k0] = *(bf16x8*)&pk;
    }
  } else {
    uint4 z = {0, 0, 0, 0};
#pragma unroll
    for (int k0 = 0; k0 < 8; ++k0) afrag[k0] = *(bf16x8*)&z;
  }
#pragma unroll
  for (int n0 = 0; n0 < 8; ++n0) {
    f32x4 acc = {0.f, 0.f, 0.f, 0.f};
    const unsigned short* wrow = Wt1 + (size_t)(n0 * 16 + idx16) * IN + quad * 8;
#pragma unroll
    for (int k0 = 0; k0 < 8; ++k0) {
      bf16x8 bfrag = *(const bf16x8*)(wrow + k0 * 32);
      acc = __builtin_amdgcn_mfma_f32_16x16x32_bf16(afrag[k0], bfrag, acc, 0, 0, 0);
    }
    int n = n0 * 16 + idx16;
    float sc = g1[n] * rsqrtf(v1[n] + EPS);
    float ad = b1[n] - m1[n];
    float bb = be1[n];
#pragma unroll
    for (int r = 0; r < 4; ++r) {
      int mm = m_base + quad * 4 + r;
      float val = fmaxf((acc[r] + ad) * sc + bb, 0.f);
      h1bf[(size_t)mm * H + n] = bf16_1(val);
    }
  }
}

// One wave per node: normalize csr weights in place (w /= max(wsum[src],1)).
__device__ void norm_body(int bid, const int* __restrict__ cnt, const float* __restrict__ wsum,
                          uint2* __restrict__ csr) {
  int wave = threadIdx.x >> 6;
  int lane = threadIdx.x & 63;
  int node = bid * 4 + wave;
  if (node >= N) return;
  int deg = min(cnt[node], CAP);
  if (lane < deg) {
    size_t slot = (size_t)node * CAP + lane;
    uint2 e = csr[slot];
    float w = __uint_as_float(e.y) / fmaxf(wsum[e.x], 1.0f);
    csr[slot] = make_uint2(e.x, __float_as_uint(w));
  }
}

__device__ void mlp2_body(int bid, const unsigned short* __restrict__ h1bf,
                          const unsigned short* __restrict__ Wt2,
                          const float* __restrict__ b2, const float* __restrict__ g2,
                          const float* __restrict__ be2, const float* __restrict__ m2,
                          const float* __restrict__ v2, unsigned short* __restrict__ h0bf,
                          float* __restrict__ fused, const float* __restrict__ wk) {
  int wave = threadIdx.x >> 6;
  int lane = threadIdx.x & 63;
  int m_base = bid * 64 + wave * 16;
  int idx16 = lane & 15;
  int quad = lane >> 4;
  bf16x8 afrag[4];
  const unsigned short* arow = h1bf + (size_t)(m_base + idx16) * H + quad * 8;
#pragma unroll
  for (int k0 = 0; k0 < 4; ++k0) afrag[k0] = *(const bf16x8*)(arow + k0 * 32);
  float w0 = wk[0];
#pragma unroll
  for (int n0 = 0; n0 < 8; ++n0) {
    f32x4 acc = {0.f, 0.f, 0.f, 0.f};
    const unsigned short* wrow = Wt2 + (size_t)(n0 * 16 + idx16) * H + quad * 8;
#pragma unroll
    for (int k0 = 0; k0 < 4; ++k0) {
      bf16x8 bfrag = *(const bf16x8*)(wrow + k0 * 32);
      acc = __builtin_amdgcn_mfma_f32_16x16x32_bf16(afrag[k0], bfrag, acc, 0, 0, 0);
    }
    int n = n0 * 16 + idx16;
    float sc = g2[n] * rsqrtf(v2[n] + EPS);
    float ad = b2[n] - m2[n];
    float bb = be2[n];
#pragma unroll
    for (int r = 0; r < 4; ++r) {
      int m = m_base + quad * 4 + r;
      if (m < N) {
        float idv = bf16_f(h1bf[(size_t)m * H + n]);
        float val = fmaxf((acc[r] + ad) * sc + bb, 0.f) + idv;
        h0bf[(size_t)m * H + n] = bf16_1(val);
        fused[(size_t)m * H + n] = w0 * val;
      }
    }
  }
}

__global__ __launch_bounds__(256) void norm_mlp2_kernel(
    const int* __restrict__ cnt, const float* __restrict__ wsum,
    uint2* __restrict__ csr,
    const unsigned short* __restrict__ h1bf, const unsigned short* __restrict__ Wt2,
    const float* __restrict__ b2, const float* __restrict__ g2,
    const float* __restrict__ be2, const float* __restrict__ m2,
    const float* __restrict__ v2, unsigned short* __restrict__ h0bf,
    float* __restrict__ fused, const float* __restrict__ wk) {
  if ((int)blockIdx.x < NORM_BLOCKS)
    norm_body(blockIdx.x, cnt, wsum, csr);
  else
    mlp2_body(blockIdx.x - NORM_BLOCKS, h1bf, Wt2, b2, g2, be2, m2, v2, h0bf, fused, wk);
}

// APPNP SpMV (R7 geometry, measured 42.5us): quarter-wave (16 lanes x uint4 =
// 256B row) per edge, 4 edges per gather instruction; 4-quad unroll = 16 edges
// (4KB) in flight per wave. Contiguous edge list, no chunking (R9's chunked
// sweep fragmented the gather stream -> 2x regression).
__global__ __launch_bounds__(256) void prop_kernel(
    const unsigned short* __restrict__ hk, const unsigned short* __restrict__ h0,
    unsigned short* __restrict__ outb,
    const int* __restrict__ cnt, const uint2* __restrict__ csr,
    float* __restrict__ fused, const float* __restrict__ wk, int wj) {
  int wave = threadIdx.x >> 6;
  int lane = threadIdx.x & 63;
  int quarter = lane >> 4;
  int colb = (lane & 15) * 8;       // 8 bf16 cols = 16B
  int node0 = (blockIdx.x * 4 + wave) * NPW;
  float wj_w = (wj >= 0) ? wk[wj] : 0.f;
  for (int nn = 0; nn < NPW; ++nn) {
    int node = node0 + nn;          // < NPAD by construction; pads have cnt 0
    int deg = min(cnt[node], CAP);
    int beg = node * CAP;
    int end = beg + deg;
    float a[8];
#pragma unroll
    for (int j = 0; j < 8; ++j) a[j] = 0.f;
    int nfull = deg >> 2;
    int qi = 0;
    for (; qi + 4 <= nfull; qi += 4) {
      uint2 ce[4];
      uint4 rv[4];
#pragma unroll
      for (int u = 0; u < 4; ++u) ce[u] = csr[beg + (qi + u) * 4 + quarter];
#pragma unroll
      for (int u = 0; u < 4; ++u) rv[u] = *(const uint4*)&hk[(size_t)ce[u].x * H + colb];
#pragma unroll
      for (int u = 0; u < 4; ++u) {
        float w = __uint_as_float(ce[u].y);
        a[0] += w * bf16_lo(rv[u].x); a[1] += w * bf16_hi(rv[u].x);
        a[2] += w * bf16_lo(rv[u].y); a[3] += w * bf16_hi(rv[u].y);
        a[4] += w * bf16_lo(rv[u].z); a[5] += w * bf16_hi(rv[u].z);
        a[6] += w * bf16_lo(rv[u].w); a[7] += w * bf16_hi(rv[u].w);
      }
    }
    for (; qi < nfull; ++qi) {
      uint2 ce = csr[beg + qi * 4 + quarter];
      uint4 rv = *(const uint4*)&hk[(size_t)ce.x * H + colb];
      float w = __uint_as_float(ce.y);
      a[0] += w * bf16_lo(rv.x); a[1] += w * bf16_hi(rv.x);
      a[2] += w * bf16_lo(rv.y); a[3] += w * bf16_hi(rv.y);
      a[4] += w * bf16_lo(rv.z); a[5] += w * bf16_hi(rv.z);
      a[6] += w * bf16_lo(rv.w); a[7] += w * bf16_hi(rv.w);
    }
    if (deg & 3) {
      int e = beg + nfull * 4 + quarter;
      bool valid = e < end;
      uint2 ce = csr[valid ? e : beg];
      float w = valid ? __uint_as_float(ce.y) : 0.f;
      uint4 rv = *(const uint4*)&hk[(size_t)ce.x * H + colb];
      a[0] += w * bf16_lo(rv.x); a[1] += w * bf16_hi(rv.x);
      a[2] += w * bf16_lo(rv.y); a[3] += w * bf16_hi(rv.y);
      a[4] += w * bf16_lo(rv.z); a[5] += w * bf16_hi(rv.z);
      a[6] += w * bf16_lo(rv.w); a[7] += w * bf16_hi(rv.w);
    }
#pragma unroll
    for (int j = 0; j < 8; ++j) {
      a[j] += __shfl_xor(a[j], 16, 64);
      a[j] += __shfl_xor(a[j], 32, 64);
    }
    size_t idx = (size_t)node * H + colb;
    if (quarter == 0) {
      uint4 hv = *(const uint4*)&h0[idx];
      float v0 = (1.f - ALPHA) * a[0] + ALPHA * bf16_lo(hv.x);
      float v1 = (1.f - ALPHA) * a[1] + ALPHA * bf16_hi(hv.x);
      float v2 = (1.f - ALPHA) * a[2] + ALPHA * bf16_lo(hv.y);
      float v3 = (1.f - ALPHA) * a[3] + ALPHA * bf16_hi(hv.y);
      float v4 = (1.f - ALPHA) * a[4] + ALPHA * bf16_lo(hv.z);
      float v5 = (1.f - ALPHA) * a[5] + ALPHA * bf16_hi(hv.z);
      float v6 = (1.f - ALPHA) * a[6] + ALPHA * bf16_lo(hv.w);
      float v7 = (1.f - ALPHA) * a[7] + ALPHA * bf16_hi(hv.w);
      uint4 pk;
      pk.x = pack2_bf16(v0, v1);
      pk.y = pack2_bf16(v2, v3);
      pk.z = pack2_bf16(v4, v5);
      pk.w = pack2_bf16(v6, v7);
      *(uint4*)&outb[idx] = pk;
    } else if (quarter == 1 && wj >= 0 && node < N) {
      uint4 hv = *(const uint4*)&h0[idx];
      float v0 = (1.f - ALPHA) * a[0] + ALPHA * bf16_lo(hv.x);
      float v1 = (1.f - ALPHA) * a[1] + ALPHA * bf16_hi(hv.x);
      float v2 = (1.f - ALPHA) * a[2] + ALPHA * bf16_lo(hv.y);
      float v3 = (1.f - ALPHA) * a[3] + ALPHA * bf16_hi(hv.y);
      float v4 = (1.f - ALPHA) * a[4] + ALPHA * bf16_lo(hv.z);
      float v5 = (1.f - ALPHA) * a[5] + ALPHA * bf16_hi(hv.z);
      float v6 = (1.f - ALPHA) * a[6] + ALPHA * bf16_lo(hv.w);
      float v7 = (1.f - ALPHA) * a[7] + ALPHA * bf16_hi(hv.w);
      float4 f0 = *(float4*)&fused[idx];
      float4 f1 = *(float4*)&fused[idx + 4];
      f0.x += wj_w * v0; f0.y += wj_w * v1; f0.z += wj_w * v2; f0.w += wj_w * v3;
      f1.x += wj_w * v4; f1.y += wj_w * v5; f1.z += wj_w * v6; f1.w += wj_w * v7;
      *(float4*)&fused[idx] = f0;
      *(float4*)&fused[idx + 4] = f1;
    }
  }
}

// hid = relu(bn3(fused @ W3 + b3)); out = hid @ W4 + b4
__global__ __launch_bounds__(64) void head_kernel(
    const float* __restrict__ fused, const float* __restrict__ W3,
    const float* __restrict__ b3, const float* __restrict__ g3,
    const float* __restrict__ be3, const float* __restrict__ m3,
    const float* __restrict__ v3, const float* __restrict__ W4,
    const float* __restrict__ b4, float* __restrict__ out) {
  __shared__ float fl[16][H];
  __shared__ float hl[16][H2v];
  int node0 = blockIdx.x * 16;
  int t = threadIdx.x;
  for (int idx = t * 4; idx < 16 * H; idx += 64 * 4) {
    int r = idx >> 7, c = idx & (H - 1);
    *(float4*)&fl[r][c] = *(const float4*)&fused[(size_t)(node0 + r) * H + c];
  }
  __syncthreads();
  {
    int ng = t >> 4;
    int c0 = (t & 15) * 4;
    float acc[4][4];
#pragma unroll
    for (int a = 0; a < 4; ++a)
#pragma unroll
      for (int b = 0; b < 4; ++b) acc[a][b] = 0.f;
    for (int k = 0; k < H; k += 4) {
      float4 xv[4];
#pragma unroll
      for (int a = 0; a < 4; ++a) xv[a] = *(const float4*)&fl[ng * 4 + a][k];
      float4 wv[4];
#pragma unroll
      for (int j = 0; j < 4; ++j) wv[j] = *(const float4*)&W3[(size_t)(k + j) * H2v + c0];
#pragma unroll
      for (int a = 0; a < 4; ++a) {
        float xa0 = xv[a].x, xa1 = xv[a].y, xa2 = xv[a].z, xa3 = xv[a].w;
        acc[a][0] += xa0 * wv[0].x + xa1 * wv[1].x + xa2 * wv[2].x + xa3 * wv[3].x;
        acc[a][1] += xa0 * wv[0].y + xa1 * wv[1].y + xa2 * wv[2].y + xa3 * wv[3].y;
        acc[a][2] += xa0 * wv[0].z + xa1 * wv[1].z + xa2 * wv[2].z + xa3 * wv[3].z;
        acc[a][3] += xa0 * wv[0].w + xa1 * wv[1].w + xa2 * wv[2].w + xa3 * wv[3].w;
      }
    }
    float sc[4], ad[4], bb[4];
#pragma unroll
    for (int b = 0; b < 4; ++b) {
      int c = c0 + b;
      sc[b] = g3[c] * rsqrtf(v3[c] + EPS);
      ad[b] = b3[c] - m3[c];
      bb[b] = be3[c];
    }
#pragma unroll
    for (int a = 0; a < 4; ++a)
#pragma unroll
      for (int b = 0; b < 4; ++b)
        hl[ng * 4 + a][c0 + b] = fmaxf((acc[a][b] + ad[b]) * sc[b] + bb[b], 0.f);
  }
  __syncthreads();
  {
    int co = t & 31;
    int nh = t >> 5;
    float bias = b4[co];
#pragma unroll
    for (int a = 0; a < 8; ++a) {
      int nloc = nh * 8 + a;
      float accf = bias;
      for (int k = 0; k < H2v; k += 4) {
        float4 hv = *(const float4*)&hl[nloc][k];
        accf += hv.x * W4[(size_t)(k + 0) * O + co];
        accf += hv.y * W4[(size_t)(k + 1) * O + co];
        accf += hv.z * W4[(size_t)(k + 2) * O + co];
        accf += hv.w * W4[(size_t)(k + 3) * O + co];
      }
      out[(size_t)(node0 + nloc) * O + co] = accf;
    }
  }
}

}  // namespace

extern "C" void kernel_launch(void* const* d_in, const int* in_sizes, int n_in,
                              void* d_out, int out_size, void* d_ws, size_t ws_size,
                              hipStream_t stream) {
  const float* x   = (const float*)d_in[0];
  const int*   ei  = (const int*)d_in[1];
  const float* ew  = (const float*)d_in[2];
  const float* W1  = (const float*)d_in[3];
  const float* b1  = (const float*)d_in[4];
  const float* g1  = (const float*)d_in[5];
  const float* be1 = (const float*)d_in[6];
  const float* m1  = (const float*)d_in[7];
  const float* v1  = (const float*)d_in[8];
  const float* W2  = (const float*)d_in[9];
  const float* b2  = (const float*)d_in[10];
  const float* g2  = (const float*)d_in[11];
  const float* be2 = (const float*)d_in[12];
  const float* m2  = (const float*)d_in[13];
  const float* v2  = (const float*)d_in[14];
  const float* att = (const float*)d_in[15];
  const float* W3  = (const float*)d_in[16];
  const float* b3  = (const float*)d_in[17];
  const float* g3  = (const float*)d_in[18];
  const float* be3 = (const float*)d_in[19];
  const float* m3  = (const float*)d_in[20];
  const float* v3  = (const float*)d_in[21];
  const float* W4  = (const float*)d_in[22];
  const float* b4  = (const float*)d_in[23];
  const int* row = ei;
  const int* col = ei + E;
  float* out = (float*)d_out;

  char* p = (char*)d_ws;
  auto carve = [&](size_t bytes) -> void* {
    void* q = (void*)p;
    p += (bytes + 255) & ~(size_t)255;
    return q;
  };
  int*      cnt  = (int*)carve((size_t)NPAD * 4);
  float*    wsum = (float*)carve((size_t)N * 4);
  uint2*    csr  = (uint2*)carve((size_t)N * CAP * 8);
  float*    wk   = (float*)carve(64);
  unsigned short* Wt1  = (unsigned short*)carve((size_t)H * IN * 2);
  unsigned short* Wt2  = (unsigned short*)carve((size_t)H * H * 2);
  unsigned short* h1bf = (unsigned short*)carve((size_t)NPAD * H * 2);
  unsigned short* bf0  = (unsigned short*)carve((size_t)NPAD * H * 2);
  unsigned short* bfA  = (unsigned short*)carve((size_t)NPAD * H * 2);
  unsigned short* bfB  = (unsigned short*)carve((size_t)NPAD * H * 2);
  float* fused = (float*)carve((size_t)N * H * 4);

  const int tb = 256;
  init_kernel<<<(NPAD + tb - 1) / tb, tb, 0, stream>>>(cnt, wsum, att, wk);
  conv_wt_kernel<<<(H * (IN / 8) + tb - 1) / tb, tb, 0, stream>>>(W1, Wt1, IN);
  conv_wt_kernel<<<(H * (H / 8) + tb - 1) / tb, tb, 0, stream>>>(W2, Wt2, H);

  fused_fill_kernel<<<(E + tb - 1) / tb, tb, 0, stream>>>(row, col, ew, cnt, wsum, csr);
  mlp1_mfma_kernel<<<MLP_BLOCKS, 256, 0, stream>>>(x, Wt1, b1, g1, be1, m1, v1, h1bf);
  norm_mlp2_kernel<<<NORM_BLOCKS + MLP_BLOCKS, 256, 0, stream>>>(
      cnt, wsum, csr, h1bf, Wt2, b2, g2, be2, m2, v2, bf0, fused, wk);

  // APPNP propagation: 5 outer x 5 inner; 3 rotating bf16 buffers.
  unsigned short* h0 = bf0;
  unsigned short* pa = bfA;
  unsigned short* pb = bfB;
  for (int j = 1; j <= K; ++j) {
    const unsigned short* src = h0;
    unsigned short* dst = pa;
    for (int i = 0; i < K; ++i) {
      int wj = (i == K - 1) ? j : -1;
      prop_kernel<<<PROP_BLOCKS, 256, 0, stream>>>(src, h0, dst, cnt, csr, fused, wk, wj);
      if (i < K - 1) {
        src = dst;
        dst = (dst == pa) ? pb : pa;
      }
    }
    unsigned short* oldh0 = h0;
    h0 = pa;
    pa = pb;
    pb = oldh0;
  }

  head_kernel<<<N / 16, 64, 0, stream>>>(fused, W3, b3, g3, be3, m3, v3, W4, b4, out);
}